// Round 1
// baseline (1659.178 us; speedup 1.0000x reference)
//
#include <hip/hip_runtime.h>
#include <hip/hip_bf16.h>

// LightGCN-M: projection + 3-layer graph propagation + batched dot.
// Sizes fixed by the reference.
#define NU 50000
#define NI 30000
#define NN 80000   // NU + NI
#define KDIM 64
#define DD0 768
#define DD1 128
#define DD 896     // DD0 + DD1

// ---------------------------------------------------------------------------
// 1) F_proj = l2norm(concat(F0,F1) @ W + b), written into x rows [NU, NN).
// Block = 256 (4 waves). Each wave computes 4 rows; lane k owns output col k.
// Feature rows staged in LDS; W streamed (L2-resident, 229 KB).
// ---------------------------------------------------------------------------
__global__ __launch_bounds__(256) void proj_kernel(
    const float* __restrict__ F0, const float* __restrict__ F1,
    const float* __restrict__ W, const float* __restrict__ b,
    float* __restrict__ x)
{
    __shared__ float feat[16][DD];   // 16 rows * 896 f32 = 57,344 B
    const int tid  = threadIdx.x;
    const int wave = tid >> 6;
    const int lane = tid & 63;
    const int rowBase = blockIdx.x * 16;

    // stage: each wave stages its own 4 rows (coalesced)
    for (int rr = 0; rr < 4; ++rr) {
        const int rLoc = wave * 4 + rr;
        const int r = rowBase + rLoc;
        if (r < NI) {
            for (int d = lane; d < DD; d += 64) {
                float v = (d < DD0) ? F0[(size_t)r * DD0 + d]
                                    : F1[(size_t)r * DD1 + (d - DD0)];
                feat[rLoc][d] = v;
            }
        }
    }
    __syncthreads();

    const float bk = b[lane];
    float acc[4] = {bk, bk, bk, bk};
    const int rLocBase = wave * 4;
    for (int d = 0; d < DD; ++d) {
        const float w = W[d * KDIM + lane];   // coalesced; L2-hit
        #pragma unroll
        for (int rr = 0; rr < 4; ++rr)
            acc[rr] += feat[rLocBase + rr][d] * w;   // LDS broadcast
    }

    #pragma unroll
    for (int rr = 0; rr < 4; ++rr) {
        const int r = rowBase + rLocBase + rr;
        if (r >= NI) continue;
        const float y = acc[rr];
        float ss = y * y;
        #pragma unroll
        for (int m = 32; m >= 1; m >>= 1) ss += __shfl_xor(ss, m);
        const float n = fmaxf(sqrtf(ss), 1e-12f);
        x[(size_t)(NU + r) * KDIM + lane] = y / n;
    }
}

// ---------------------------------------------------------------------------
// 2) degree: deg[dst[e]] += 1
// ---------------------------------------------------------------------------
__global__ void degree_kernel(const int* __restrict__ dst,
                              float* __restrict__ deg, int E)
{
    const int e = blockIdx.x * blockDim.x + threadIdx.x;
    if (e < E) atomicAdd(&deg[dst[e]], 1.0f);
}

// deg -> dinv in place
__global__ void dinv_kernel(float* __restrict__ deg, int n)
{
    const int i = blockIdx.x * blockDim.x + threadIdx.x;
    if (i < n) {
        const float d = deg[i];
        deg[i] = (d > 0.0f) ? rsqrtf(fmaxf(d, 1.0f)) : 0.0f;
    }
}

// ---------------------------------------------------------------------------
// 3) scatter: nxt[dst] += cur[src] * dinv[src]*dinv[dst].  One wave per edge,
// lane k owns element k. Gather coalesced (256 B row), scatter via atomicAdd.
// ---------------------------------------------------------------------------
__global__ __launch_bounds__(256) void scatter_kernel(
    const float* __restrict__ cur, float* __restrict__ nxt,
    const int* __restrict__ src, const int* __restrict__ dst,
    const float* __restrict__ dinv, int E)
{
    const int wid  = (blockIdx.x * blockDim.x + threadIdx.x) >> 6;
    const int lane = threadIdx.x & 63;
    if (wid >= E) return;
    const int s = src[wid];
    const int d = dst[wid];
    const float w = dinv[s] * dinv[d];
    const float v = cur[(size_t)s * KDIM + lane] * w;
    atomicAdd(&nxt[(size_t)d * KDIM + lane], v);
}

// acc += nxt (float4)
__global__ void add_kernel(float* __restrict__ acc,
                           const float* __restrict__ nxt, int n4)
{
    const int i = blockIdx.x * blockDim.x + threadIdx.x;
    if (i < n4) {
        float4 a = ((const float4*)acc)[i];
        const float4 v = ((const float4*)nxt)[i];
        a.x += v.x; a.y += v.y; a.z += v.z; a.w += v.w;
        ((float4*)acc)[i] = a;
    }
}

// ---------------------------------------------------------------------------
// 4) xui[b] = (1/16) * dot(acc[user[b]], acc[NU + item[b]])   (mean/4 each)
// ---------------------------------------------------------------------------
__global__ __launch_bounds__(256) void out_kernel(
    const float* __restrict__ acc, const int* __restrict__ uidx,
    const int* __restrict__ iidx, float* __restrict__ out, int B)
{
    const int wid  = (blockIdx.x * blockDim.x + threadIdx.x) >> 6;
    const int lane = threadIdx.x & 63;
    if (wid >= B) return;
    const int u  = uidx[wid];
    const int it = iidx[wid];
    float p = acc[(size_t)u * KDIM + lane] * acc[(size_t)(NU + it) * KDIM + lane];
    #pragma unroll
    for (int m = 32; m >= 1; m >>= 1) p += __shfl_xor(p, m);
    if (lane == 0) out[wid] = p * (1.0f / 16.0f);
}

extern "C" void kernel_launch(void* const* d_in, const int* in_sizes, int n_in,
                              void* d_out, int out_size, void* d_ws, size_t ws_size,
                              hipStream_t stream)
{
    const float* Gu = (const float*)d_in[0];
    const float* F0 = (const float*)d_in[1];
    const float* F1 = (const float*)d_in[2];
    const float* W  = (const float*)d_in[3];
    const float* pb = (const float*)d_in[4];
    const int* edge = (const int*)d_in[5];
    const int* uidx = (const int*)d_in[6];
    const int* iidx = (const int*)d_in[7];
    const int E = in_sizes[5] / 2;       // 2,000,000 directed edges
    const int B = in_sizes[6];           // 4096
    const int* srcp = edge;
    const int* dstp = edge + E;

    float* xA  = (float*)d_ws;                 // NN*K
    float* xB  = xA  + (size_t)NN * KDIM;      // NN*K
    float* acc = xB  + (size_t)NN * KDIM;      // NN*K
    float* deg = acc + (size_t)NN * KDIM;      // NN  (becomes dinv in place)

    // x[0:NU] = Gu
    hipMemcpyAsync(xA, Gu, (size_t)NU * KDIM * sizeof(float),
                   hipMemcpyDeviceToDevice, stream);
    // x[NU:NN] = l2norm(F @ W + b)
    proj_kernel<<<(NI + 15) / 16, 256, 0, stream>>>(F0, F1, W, pb, xA);

    // degrees -> dinv
    hipMemsetAsync(deg, 0, NN * sizeof(float), stream);
    degree_kernel<<<(E + 255) / 256, 256, 0, stream>>>(dstp, deg, E);
    dinv_kernel<<<(NN + 255) / 256, 256, 0, stream>>>(deg, NN);

    // acc = x (layer 0)
    hipMemcpyAsync(acc, xA, (size_t)NN * KDIM * sizeof(float),
                   hipMemcpyDeviceToDevice, stream);

    float* cur = xA;
    float* nxt = xB;
    const size_t xBytes = (size_t)NN * KDIM * sizeof(float);
    for (int l = 0; l < 3; ++l) {
        hipMemsetAsync(nxt, 0, xBytes, stream);
        scatter_kernel<<<(int)(((size_t)E * 64 + 255) / 256), 256, 0, stream>>>(
            cur, nxt, srcp, dstp, deg, E);
        add_kernel<<<(NN * KDIM / 4 + 255) / 256, 256, 0, stream>>>(
            acc, nxt, NN * KDIM / 4);
        float* t = cur; cur = nxt; nxt = t;
    }

    out_kernel<<<(int)(((size_t)B * 64 + 255) / 256), 256, 0, stream>>>(
        acc, uidx, iidx, (float*)d_out, B);
}

// Round 2
// 662.555 us; speedup vs baseline: 2.5042x; 2.5042x over previous
//
#include <hip/hip_runtime.h>
#include <hip/hip_bf16.h>

#define NU 50000
#define NI 30000
#define NN 80000   // NU + NI
#define KDIM 64
#define DD0 768
#define DD1 128
#define DD 896     // DD0 + DD1

// ---------------------------------------------------------------------------
// 1) F_proj = l2norm(concat(F0,F1) @ W + b), written into x rows [NU, NN).
// ---------------------------------------------------------------------------
__global__ __launch_bounds__(256) void proj_kernel(
    const float* __restrict__ F0, const float* __restrict__ F1,
    const float* __restrict__ W, const float* __restrict__ b,
    float* __restrict__ x)
{
    __shared__ float feat[16][DD];   // 16 rows * 896 f32 = 57,344 B
    const int tid  = threadIdx.x;
    const int wave = tid >> 6;
    const int lane = tid & 63;
    const int rowBase = blockIdx.x * 16;

    for (int rr = 0; rr < 4; ++rr) {
        const int rLoc = wave * 4 + rr;
        const int r = rowBase + rLoc;
        if (r < NI) {
            for (int d = lane; d < DD; d += 64) {
                float v = (d < DD0) ? F0[(size_t)r * DD0 + d]
                                    : F1[(size_t)r * DD1 + (d - DD0)];
                feat[rLoc][d] = v;
            }
        }
    }
    __syncthreads();

    const float bk = b[lane];
    float acc[4] = {bk, bk, bk, bk};
    const int rLocBase = wave * 4;
    for (int d = 0; d < DD; ++d) {
        const float w = W[d * KDIM + lane];
        #pragma unroll
        for (int rr = 0; rr < 4; ++rr)
            acc[rr] += feat[rLocBase + rr][d] * w;
    }

    #pragma unroll
    for (int rr = 0; rr < 4; ++rr) {
        const int r = rowBase + rLocBase + rr;
        if (r >= NI) continue;
        const float y = acc[rr];
        float ss = y * y;
        #pragma unroll
        for (int m = 32; m >= 1; m >>= 1) ss += __shfl_xor(ss, m);
        const float n = fmaxf(sqrtf(ss), 1e-12f);
        x[(size_t)(NU + r) * KDIM + lane] = y / n;
    }
}

// ---------------------------------------------------------------------------
// CSR build: histogram -> exclusive scan -> dinv -> bucket fill
// ---------------------------------------------------------------------------
__global__ void hist_kernel(const int* __restrict__ dst,
                            int* __restrict__ cnt, int E)
{
    const int e = blockIdx.x * blockDim.x + threadIdx.x;
    if (e < E) atomicAdd(&cnt[dst[e]], 1);
}

// per-256 block exclusive scan; emits block totals
__global__ void scanA_kernel(const int* __restrict__ cnt,
                             int* __restrict__ off,
                             int* __restrict__ bsum, int n)
{
    __shared__ int s[256];
    const int t = threadIdx.x;
    const int i = blockIdx.x * 256 + t;
    const int v = (i < n) ? cnt[i] : 0;
    s[t] = v;
    __syncthreads();
    for (int d = 1; d < 256; d <<= 1) {
        const int u = (t >= d) ? s[t - d] : 0;
        __syncthreads();
        s[t] += u;
        __syncthreads();
    }
    if (i < n) off[i] = s[t] - v;           // exclusive
    if (t == 255) bsum[blockIdx.x] = s[255]; // block total
}

// single-block exclusive scan of block sums (nb <= 512)
__global__ void scanB_kernel(int* __restrict__ bsum, int nb)
{
    __shared__ int s[512];
    const int t = threadIdx.x;
    const int v = (t < nb) ? bsum[t] : 0;
    s[t] = v;
    __syncthreads();
    for (int d = 1; d < 512; d <<= 1) {
        const int u = (t >= d) ? s[t - d] : 0;
        __syncthreads();
        s[t] += u;
        __syncthreads();
    }
    if (t < nb) bsum[t] = s[t] - v;         // exclusive block offsets
}

__global__ void scanC_kernel(int* __restrict__ off,
                             const int* __restrict__ bsum, int n)
{
    const int i = blockIdx.x * blockDim.x + threadIdx.x;
    if (i < n) off[i] += bsum[blockIdx.x];
}

__global__ void dinv_kernel(const int* __restrict__ cnt,
                            float* __restrict__ dinv, int n)
{
    const int i = blockIdx.x * blockDim.x + threadIdx.x;
    if (i < n) {
        const int d = cnt[i];
        dinv[i] = (d > 0) ? rsqrtf((float)d) : 0.0f;   // deg>=1 when >0
    }
}

__global__ void fill_kernel(const int* __restrict__ src,
                            const int* __restrict__ dst,
                            const int* __restrict__ off,
                            int* __restrict__ cursor,
                            const float* __restrict__ dinv,
                            int* __restrict__ col,
                            float* __restrict__ wgt, int E)
{
    const int e = blockIdx.x * blockDim.x + threadIdx.x;
    if (e < E) {
        const int d = dst[e];
        const int s = src[e];
        const int pos = off[d] + atomicAdd(&cursor[d], 1);
        col[pos] = s;
        wgt[pos] = dinv[s] * dinv[d];
    }
}

// ---------------------------------------------------------------------------
// 3) pull: nxt[row] = sum_j wgt * cur[col_j];  acc[row] += nxt[row]
// One wave per dst row; lane k owns element k.
// ---------------------------------------------------------------------------
__global__ __launch_bounds__(256) void pull_kernel(
    const float* __restrict__ cur, float* __restrict__ nxt,
    float* __restrict__ acc,
    const int* __restrict__ off, const int* __restrict__ cnt,
    const int* __restrict__ col, const float* __restrict__ wgt)
{
    const int row  = (blockIdx.x * blockDim.x + threadIdx.x) >> 6;
    const int lane = threadIdx.x & 63;
    if (row >= NN) return;
    const int base = off[row];
    const int n    = cnt[row];
    float a = 0.0f;
    int j = 0;
    for (; j + 4 <= n; j += 4) {           // 4-deep MLP on the gathers
        const int   s0 = col[base + j + 0];
        const int   s1 = col[base + j + 1];
        const int   s2 = col[base + j + 2];
        const int   s3 = col[base + j + 3];
        const float w0 = wgt[base + j + 0];
        const float w1 = wgt[base + j + 1];
        const float w2 = wgt[base + j + 2];
        const float w3 = wgt[base + j + 3];
        const float v0 = cur[(size_t)s0 * KDIM + lane];
        const float v1 = cur[(size_t)s1 * KDIM + lane];
        const float v2 = cur[(size_t)s2 * KDIM + lane];
        const float v3 = cur[(size_t)s3 * KDIM + lane];
        a += w0 * v0 + w1 * v1 + w2 * v2 + w3 * v3;
    }
    for (; j < n; ++j) {
        const int   s = col[base + j];
        const float w = wgt[base + j];
        a += w * cur[(size_t)s * KDIM + lane];
    }
    nxt[(size_t)row * KDIM + lane] = a;
    acc[(size_t)row * KDIM + lane] += a;
}

// ---------------------------------------------------------------------------
// 4) xui[b] = (1/16) * dot(acc[user[b]], acc[NU + item[b]])
// ---------------------------------------------------------------------------
__global__ __launch_bounds__(256) void out_kernel(
    const float* __restrict__ acc, const int* __restrict__ uidx,
    const int* __restrict__ iidx, float* __restrict__ out, int B)
{
    const int wid  = (blockIdx.x * blockDim.x + threadIdx.x) >> 6;
    const int lane = threadIdx.x & 63;
    if (wid >= B) return;
    const int u  = uidx[wid];
    const int it = iidx[wid];
    float p = acc[(size_t)u * KDIM + lane] * acc[(size_t)(NU + it) * KDIM + lane];
    #pragma unroll
    for (int m = 32; m >= 1; m >>= 1) p += __shfl_xor(p, m);
    if (lane == 0) out[wid] = p * (1.0f / 16.0f);
}

extern "C" void kernel_launch(void* const* d_in, const int* in_sizes, int n_in,
                              void* d_out, int out_size, void* d_ws, size_t ws_size,
                              hipStream_t stream)
{
    const float* Gu = (const float*)d_in[0];
    const float* F0 = (const float*)d_in[1];
    const float* F1 = (const float*)d_in[2];
    const float* W  = (const float*)d_in[3];
    const float* pb = (const float*)d_in[4];
    const int* edge = (const int*)d_in[5];
    const int* uidx = (const int*)d_in[6];
    const int* iidx = (const int*)d_in[7];
    const int E = in_sizes[5] / 2;       // 2,000,000 directed edges
    const int B = in_sizes[6];           // 4096
    const int* srcp = edge;
    const int* dstp = edge + E;

    const size_t XE = (size_t)NN * KDIM;          // 5,120,000 floats
    float* xA    = (float*)d_ws;                  // XE
    float* xB    = xA + XE;                       // XE
    float* acc   = xB + XE;                       // XE
    float* dinv  = acc + XE;                      // NN
    int*   cnt   = (int*)(dinv + NN);             // NN
    int*   off   = cnt + NN;                      // NN
    int*   cursor= off + NN;                      // NN
    int*   bsum  = cursor + NN;                   // 512
    int*   col   = bsum + 512;                    // E
    float* wgt   = (float*)(col + E);             // E

    // x0: users then projected items
    hipMemcpyAsync(xA, Gu, (size_t)NU * KDIM * sizeof(float),
                   hipMemcpyDeviceToDevice, stream);
    proj_kernel<<<(NI + 15) / 16, 256, 0, stream>>>(F0, F1, W, pb, xA);

    // CSR build
    hipMemsetAsync(cnt, 0, NN * sizeof(int), stream);
    hipMemsetAsync(cursor, 0, NN * sizeof(int), stream);
    hist_kernel<<<(E + 255) / 256, 256, 0, stream>>>(dstp, cnt, E);
    const int NB = (NN + 255) / 256;   // 313
    scanA_kernel<<<NB, 256, 0, stream>>>(cnt, off, bsum, NN);
    scanB_kernel<<<1, 512, 0, stream>>>(bsum, NB);
    scanC_kernel<<<NB, 256, 0, stream>>>(off, bsum, NN);
    dinv_kernel<<<(NN + 255) / 256, 256, 0, stream>>>(cnt, dinv, NN);
    fill_kernel<<<(E + 255) / 256, 256, 0, stream>>>(srcp, dstp, off, cursor,
                                                     dinv, col, wgt, E);

    // acc = x0
    hipMemcpyAsync(acc, xA, XE * sizeof(float), hipMemcpyDeviceToDevice, stream);

    // 3 propagation layers (pull, fused acc update)
    float* cur = xA;
    float* nxt = xB;
    for (int l = 0; l < 3; ++l) {
        pull_kernel<<<(int)((XE + 255) / 256), 256, 0, stream>>>(
            cur, nxt, acc, off, cnt, col, wgt);
        float* t = cur; cur = nxt; nxt = t;
    }

    out_kernel<<<(int)(((size_t)B * 64 + 255) / 256), 256, 0, stream>>>(
        acc, uidx, iidx, (float*)d_out, B);
}

// Round 3
// 542.082 us; speedup vs baseline: 3.0608x; 1.2222x over previous
//
#include <hip/hip_runtime.h>
#include <hip/hip_bf16.h>

#define NU 50000
#define NI 30000
#define NN 80000   // NU + NI
#define KDIM 64
#define DD0 768
#define DD1 128
#define DD 896     // DD0 + DD1 = 14 chunks of 64

// ---------------------------------------------------------------------------
// 1) F_proj = l2norm(concat(F0,F1) @ W + b) -> x rows [NU, NN).
// Tiled f32 GEMM: 64 rows x 64 cols per 256-thread block, K chunks of 64.
// Thread (ty,tx) owns a 4x4 register tile. Ft staged transposed [kk][row]
// (+4 pad keeps float4 alignment and kills bank conflicts on broadcast reads).
// ---------------------------------------------------------------------------
__global__ __launch_bounds__(256) void proj_kernel(
    const float* __restrict__ F0, const float* __restrict__ F1,
    const float* __restrict__ W, const float* __restrict__ b,
    float* __restrict__ x)
{
    __shared__ float Ft[64][68];   // [kk][rowLoc], padded
    __shared__ float Wt[64][64];   // [kk][col]

    const int tid = threadIdx.x;
    const int ty  = tid >> 4;      // 0..15 -> rows ty*4..+3
    const int tx  = tid & 15;      // 0..15 -> cols tx*4..+3
    const int rowBase = blockIdx.x * 64;

    float acc[4][4] = {};

    for (int c = 0; c < 14; ++c) {
        // ---- stage F chunk (transposed) : 64 rows x 64 k
        #pragma unroll
        for (int rep = 0; rep < 4; ++rep) {
            const int idx  = rep * 256 + tid;   // 0..1023
            const int rLoc = idx >> 4;          // 0..63
            const int kq   = idx & 15;          // float4 index in k
            const int r    = rowBase + rLoc;
            float4 v = make_float4(0.f, 0.f, 0.f, 0.f);
            if (r < NI) {
                if (c < 12)
                    v = *(const float4*)&F0[(size_t)r * DD0 + c * 64 + kq * 4];
                else
                    v = *(const float4*)&F1[(size_t)r * DD1 + (c - 12) * 64 + kq * 4];
            }
            Ft[kq * 4 + 0][rLoc] = v.x;
            Ft[kq * 4 + 1][rLoc] = v.y;
            Ft[kq * 4 + 2][rLoc] = v.z;
            Ft[kq * 4 + 3][rLoc] = v.w;
        }
        // ---- stage W chunk : 64 k x 64 cols (no transpose)
        #pragma unroll
        for (int rep = 0; rep < 4; ++rep) {
            const int idx = rep * 256 + tid;
            const int kk  = idx >> 4;
            const int cq  = idx & 15;
            *(float4*)&Wt[kk][cq * 4] =
                *(const float4*)&W[(size_t)(c * 64 + kk) * KDIM + cq * 4];
        }
        __syncthreads();

        // ---- compute
        #pragma unroll 4
        for (int kk = 0; kk < 64; ++kk) {
            const float4 a = *(const float4*)&Ft[kk][ty * 4];
            const float4 w = *(const float4*)&Wt[kk][tx * 4];
            const float av[4] = {a.x, a.y, a.z, a.w};
            const float wv[4] = {w.x, w.y, w.z, w.w};
            #pragma unroll
            for (int i = 0; i < 4; ++i)
                #pragma unroll
                for (int j = 0; j < 4; ++j)
                    acc[i][j] += av[i] * wv[j];
        }
        __syncthreads();
    }

    // ---- epilogue: bias, row L2-norm (reduce over 16 tx lanes), write
    const float4 bv = *(const float4*)&b[tx * 4];
    const float bias[4] = {bv.x, bv.y, bv.z, bv.w};
    #pragma unroll
    for (int i = 0; i < 4; ++i) {
        float y[4];
        float ss = 0.f;
        #pragma unroll
        for (int j = 0; j < 4; ++j) {
            y[j] = acc[i][j] + bias[j];
            ss += y[j] * y[j];
        }
        ss += __shfl_xor(ss, 1);
        ss += __shfl_xor(ss, 2);
        ss += __shfl_xor(ss, 4);
        ss += __shfl_xor(ss, 8);
        const float inv = 1.0f / fmaxf(sqrtf(ss), 1e-12f);
        const int r = rowBase + ty * 4 + i;
        if (r < NI) {
            float4 o;
            o.x = y[0] * inv; o.y = y[1] * inv; o.z = y[2] * inv; o.w = y[3] * inv;
            *(float4*)&x[(size_t)(NU + r) * KDIM + tx * 4] = o;
        }
    }
}

// ---------------------------------------------------------------------------
// CSR build: histogram -> exclusive scan -> dinv -> bucket fill
// ---------------------------------------------------------------------------
__global__ void hist_kernel(const int* __restrict__ dst,
                            int* __restrict__ cnt, int E)
{
    const int e = blockIdx.x * blockDim.x + threadIdx.x;
    if (e < E) atomicAdd(&cnt[dst[e]], 1);
}

__global__ void scanA_kernel(const int* __restrict__ cnt,
                             int* __restrict__ off,
                             int* __restrict__ bsum, int n)
{
    __shared__ int s[256];
    const int t = threadIdx.x;
    const int i = blockIdx.x * 256 + t;
    const int v = (i < n) ? cnt[i] : 0;
    s[t] = v;
    __syncthreads();
    for (int d = 1; d < 256; d <<= 1) {
        const int u = (t >= d) ? s[t - d] : 0;
        __syncthreads();
        s[t] += u;
        __syncthreads();
    }
    if (i < n) off[i] = s[t] - v;
    if (t == 255) bsum[blockIdx.x] = s[255];
}

__global__ void scanB_kernel(int* __restrict__ bsum, int nb)
{
    __shared__ int s[512];
    const int t = threadIdx.x;
    const int v = (t < nb) ? bsum[t] : 0;
    s[t] = v;
    __syncthreads();
    for (int d = 1; d < 512; d <<= 1) {
        const int u = (t >= d) ? s[t - d] : 0;
        __syncthreads();
        s[t] += u;
        __syncthreads();
    }
    if (t < nb) bsum[t] = s[t] - v;
}

__global__ void scanC_kernel(int* __restrict__ off,
                             const int* __restrict__ bsum, int n)
{
    const int i = blockIdx.x * blockDim.x + threadIdx.x;
    if (i < n) off[i] += bsum[blockIdx.x];
}

__global__ void dinv_kernel(const int* __restrict__ cnt,
                            float* __restrict__ dinv, int n)
{
    const int i = blockIdx.x * blockDim.x + threadIdx.x;
    if (i < n) {
        const int d = cnt[i];
        dinv[i] = (d > 0) ? rsqrtf((float)d) : 0.0f;
    }
}

__global__ void fill_kernel(const int* __restrict__ src,
                            const int* __restrict__ dst,
                            const int* __restrict__ off,
                            int* __restrict__ cursor,
                            const float* __restrict__ dinv,
                            int* __restrict__ col,
                            float* __restrict__ wgt, int E)
{
    const int e = blockIdx.x * blockDim.x + threadIdx.x;
    if (e < E) {
        const int d = dst[e];
        const int s = src[e];
        const int pos = off[d] + atomicAdd(&cursor[d], 1);
        col[pos] = s;
        wgt[pos] = dinv[s] * dinv[d];
    }
}

// ---------------------------------------------------------------------------
// 3) pull: nxt[row] = sum_j wgt * cur[col_j];  acc[row] += nxt[row]
// ---------------------------------------------------------------------------
__global__ __launch_bounds__(256) void pull_kernel(
    const float* __restrict__ cur, float* __restrict__ nxt,
    float* __restrict__ acc,
    const int* __restrict__ off, const int* __restrict__ cnt,
    const int* __restrict__ col, const float* __restrict__ wgt)
{
    const int row  = (blockIdx.x * blockDim.x + threadIdx.x) >> 6;
    const int lane = threadIdx.x & 63;
    if (row >= NN) return;
    const int base = off[row];
    const int n    = cnt[row];
    float a = 0.0f;
    int j = 0;
    for (; j + 4 <= n; j += 4) {
        const int   s0 = col[base + j + 0];
        const int   s1 = col[base + j + 1];
        const int   s2 = col[base + j + 2];
        const int   s3 = col[base + j + 3];
        const float w0 = wgt[base + j + 0];
        const float w1 = wgt[base + j + 1];
        const float w2 = wgt[base + j + 2];
        const float w3 = wgt[base + j + 3];
        const float v0 = cur[(size_t)s0 * KDIM + lane];
        const float v1 = cur[(size_t)s1 * KDIM + lane];
        const float v2 = cur[(size_t)s2 * KDIM + lane];
        const float v3 = cur[(size_t)s3 * KDIM + lane];
        a += w0 * v0 + w1 * v1 + w2 * v2 + w3 * v3;
    }
    for (; j < n; ++j) {
        const int   s = col[base + j];
        const float w = wgt[base + j];
        a += w * cur[(size_t)s * KDIM + lane];
    }
    nxt[(size_t)row * KDIM + lane] = a;
    acc[(size_t)row * KDIM + lane] += a;
}

// ---------------------------------------------------------------------------
// 4) xui[b] = (1/16) * dot(acc[user[b]], acc[NU + item[b]])
// ---------------------------------------------------------------------------
__global__ __launch_bounds__(256) void out_kernel(
    const float* __restrict__ acc, const int* __restrict__ uidx,
    const int* __restrict__ iidx, float* __restrict__ out, int B)
{
    const int wid  = (blockIdx.x * blockDim.x + threadIdx.x) >> 6;
    const int lane = threadIdx.x & 63;
    if (wid >= B) return;
    const int u  = uidx[wid];
    const int it = iidx[wid];
    float p = acc[(size_t)u * KDIM + lane] * acc[(size_t)(NU + it) * KDIM + lane];
    #pragma unroll
    for (int m = 32; m >= 1; m >>= 1) p += __shfl_xor(p, m);
    if (lane == 0) out[wid] = p * (1.0f / 16.0f);
}

extern "C" void kernel_launch(void* const* d_in, const int* in_sizes, int n_in,
                              void* d_out, int out_size, void* d_ws, size_t ws_size,
                              hipStream_t stream)
{
    const float* Gu = (const float*)d_in[0];
    const float* F0 = (const float*)d_in[1];
    const float* F1 = (const float*)d_in[2];
    const float* W  = (const float*)d_in[3];
    const float* pb = (const float*)d_in[4];
    const int* edge = (const int*)d_in[5];
    const int* uidx = (const int*)d_in[6];
    const int* iidx = (const int*)d_in[7];
    const int E = in_sizes[5] / 2;       // 2,000,000 directed edges
    const int B = in_sizes[6];           // 4096
    const int* srcp = edge;
    const int* dstp = edge + E;

    const size_t XE = (size_t)NN * KDIM;
    float* xA    = (float*)d_ws;                  // XE
    float* xB    = xA + XE;                       // XE
    float* acc   = xB + XE;                       // XE
    float* dinv  = acc + XE;                      // NN
    int*   cnt   = (int*)(dinv + NN);             // NN
    int*   off   = cnt + NN;                      // NN
    int*   cursor= off + NN;                      // NN
    int*   bsum  = cursor + NN;                   // 512
    int*   col   = bsum + 512;                    // E
    float* wgt   = (float*)(col + E);             // E

    // x0: users then projected items
    hipMemcpyAsync(xA, Gu, (size_t)NU * KDIM * sizeof(float),
                   hipMemcpyDeviceToDevice, stream);
    proj_kernel<<<(NI + 63) / 64, 256, 0, stream>>>(F0, F1, W, pb, xA);

    // CSR build
    hipMemsetAsync(cnt, 0, NN * sizeof(int), stream);
    hipMemsetAsync(cursor, 0, NN * sizeof(int), stream);
    hist_kernel<<<(E + 255) / 256, 256, 0, stream>>>(dstp, cnt, E);
    const int NB = (NN + 255) / 256;   // 313
    scanA_kernel<<<NB, 256, 0, stream>>>(cnt, off, bsum, NN);
    scanB_kernel<<<1, 512, 0, stream>>>(bsum, NB);
    scanC_kernel<<<NB, 256, 0, stream>>>(off, bsum, NN);
    dinv_kernel<<<(NN + 255) / 256, 256, 0, stream>>>(cnt, dinv, NN);
    fill_kernel<<<(E + 255) / 256, 256, 0, stream>>>(srcp, dstp, off, cursor,
                                                     dinv, col, wgt, E);

    // acc = x0
    hipMemcpyAsync(acc, xA, XE * sizeof(float), hipMemcpyDeviceToDevice, stream);

    // 3 propagation layers (pull, fused acc update)
    float* cur = xA;
    float* nxt = xB;
    for (int l = 0; l < 3; ++l) {
        pull_kernel<<<(int)((XE + 255) / 256), 256, 0, stream>>>(
            cur, nxt, acc, off, cnt, col, wgt);
        float* t = cur; cur = nxt; nxt = t;
    }

    out_kernel<<<(int)(((size_t)B * 64 + 255) / 256), 256, 0, stream>>>(
        acc, uidx, iidx, (float*)d_out, B);
}